// Round 4
// baseline (232.876 us; speedup 1.0000x reference)
//
#include <hip/hip_runtime.h>

// Haar DWT along axis 1 of (8, 4096, 1024) fp32.
// cA[b,j,c] = (x[b,2j,c] + x[b,2j+1,c]) * k,  cD = (x_even - x_odd) * k
// d_out = [cA flat | cD flat].
//
// Pure streaming (268 MB traffic). A/B matrix on this problem (kernel time):
//   NT load + NT store     : ~61-71 us (r0/r2, best so far)
//   NT load + plain store  : ~64 us    (r3, slight regression)
//   cached load + NT store : 80.5 us   (r1, measured; FETCH halved via L3
//                            but slower -> suspect NT-store interaction)
//   cached load + plain st : THIS ROUND (the m13-copy / fillBuffer config,
//                            both of which sustain 6.3-6.75 TB/s)
// Extra upside: x (134 MB) is re-read per iteration and L3-resident;
// cached loads can serve it from Infinity Cache.

#define NPAIR (8 * 2048)        // total pair-rows
#define ROWS_PER_BLOCK 8
#define NPAIR_VEC (NPAIR * 256) // vec4 elements per output half

typedef float f4 __attribute__((ext_vector_type(4)));

__global__ __launch_bounds__(256) void dwt_haar_kernel(
    const f4* __restrict__ x,
    f4* __restrict__ cA,
    f4* __restrict__ cD)
{
    const float k = 0.7071067811865476f;
    const int t = threadIdx.x;                   // vec4 column 0..255
    const int r0 = blockIdx.x * ROWS_PER_BLOCK;  // first pair-row of block

    // Preload: 16 plain global_load_dwordx4, issued back-to-back.
    f4 a[ROWS_PER_BLOCK], b[ROWS_PER_BLOCK];
#pragma unroll
    for (int j = 0; j < ROWS_PER_BLOCK; ++j) {
        const int e = (r0 + j) * 512 + t;        // even input row, vec4 units
        a[j] = x[e];
        b[j] = x[e + 256];
    }

    // Compute + store: plain stores (L2 allocate, full-line writeback).
#pragma unroll
    for (int j = 0; j < ROWS_PER_BLOCK; ++j) {
        const f4 s = (a[j] + b[j]) * k;
        const f4 d = (a[j] - b[j]) * k;
        const int o = (r0 + j) * 256 + t;
        cA[o] = s;
        cD[o] = d;
    }
}

extern "C" void kernel_launch(void* const* d_in, const int* in_sizes, int n_in,
                              void* d_out, int out_size, void* d_ws, size_t ws_size,
                              hipStream_t stream)
{
    const f4* x = (const f4*)d_in[0];
    f4* cA = (f4*)d_out;
    f4* cD = cA + NPAIR_VEC;

    const int nblocks = NPAIR / ROWS_PER_BLOCK;  // 2048 = 8 blocks/CU
    dwt_haar_kernel<<<nblocks, 256, 0, stream>>>(x, cA, cD);
}

// Round 5
// 221.785 us; speedup vs baseline: 1.0500x; 1.0500x over previous
//
#include <hip/hip_runtime.h>

// Haar DWT along axis 1 of (8, 4096, 1024) fp32.
// cA[b,j,c] = (x[b,2j,c] + x[b,2j+1,c]) * k,  cD = (x_even - x_odd) * k
// d_out = [cA flat | cD flat].
//
// Measured A/B matrix (kernel time, this problem):
//   NT load + NT store     : ~61 us (best)      <- kept
//   NT load + plain store  : ~64 us
//   cached + NT / cached + plain : 80.5 / 80.8 us (cache path throttles
//       despite L3 serving half the input -> not an HBM-side limit)
// Remaining theory: 2048 resident blocks = ~6K concurrent short streams ->
// DRAM row thrash. This version: 512 blocks (2/CU), each owning 256 KB of
// contiguous input (32 pair-rows) processed as 4 chunks of 8 with a register
// double-buffer, so streams drop 4x and 16 NT loads stay in flight across
// every store burst. Buffers are fully statically indexed (no scratch).

#define NPAIR (8 * 2048)          // total pair-rows
#define CHUNK 8                   // pair-rows per chunk
#define BLOCKS 512
#define CHUNKS_PER_BLOCK (NPAIR / (BLOCKS * CHUNK))   // 4
#define NPAIR_VEC (NPAIR * 256)   // vec4 elements per output half

typedef float f4 __attribute__((ext_vector_type(4)));

#define LOADC(A, B, RBASE)                                             \
    _Pragma("unroll")                                                  \
    for (int j = 0; j < CHUNK; ++j) {                                  \
        const int e = ((RBASE) + j) * 512 + t;                         \
        A[j] = __builtin_nontemporal_load(&x[e]);                      \
        B[j] = __builtin_nontemporal_load(&x[e + 256]);                \
    }

#define STOREC(A, B, RBASE)                                            \
    _Pragma("unroll")                                                  \
    for (int j = 0; j < CHUNK; ++j) {                                  \
        const f4 s = (A[j] + B[j]) * k;                                \
        const f4 d = (A[j] - B[j]) * k;                                \
        const int o = ((RBASE) + j) * 256 + t;                         \
        __builtin_nontemporal_store(s, &cA[o]);                        \
        __builtin_nontemporal_store(d, &cD[o]);                        \
    }

__global__ __launch_bounds__(256) void dwt_haar_kernel(
    const f4* __restrict__ x,
    f4* __restrict__ cA,
    f4* __restrict__ cD)
{
    const float k = 0.7071067811865476f;
    const int t = threadIdx.x;                          // vec4 column 0..255
    const int base = blockIdx.x * (CHUNK * CHUNKS_PER_BLOCK);

    f4 A0[CHUNK], B0[CHUNK], A1[CHUNK], B1[CHUNK];

    // Prologue: chunk 0 -> buf0.
    LOADC(A0, B0, base)

    // Steady state: prefetch next chunk into the other buffer before
    // draining/storing the current one. All buffer indices static.
#pragma unroll
    for (int cc = 0; cc < CHUNKS_PER_BLOCK / 2; ++cc) {
        const int c0 = 2 * cc;
        const int c1 = 2 * cc + 1;

        LOADC(A1, B1, base + c1 * CHUNK)          // prefetch c1
        STOREC(A0, B0, base + c0 * CHUNK)         // drain c0

        if (c1 + 1 < CHUNKS_PER_BLOCK) {
            LOADC(A0, B0, base + (c1 + 1) * CHUNK)  // prefetch c1+1
        }
        STOREC(A1, B1, base + c1 * CHUNK)         // drain c1
    }
}

extern "C" void kernel_launch(void* const* d_in, const int* in_sizes, int n_in,
                              void* d_out, int out_size, void* d_ws, size_t ws_size,
                              hipStream_t stream)
{
    const f4* x = (const f4*)d_in[0];
    f4* cA = (f4*)d_out;
    f4* cD = cA + NPAIR_VEC;

    dwt_haar_kernel<<<BLOCKS, 256, 0, stream>>>(x, cA, cD);
}

// Round 6
// 219.236 us; speedup vs baseline: 1.0622x; 1.0116x over previous
//
#include <hip/hip_runtime.h>

// Haar DWT along axis 1 of (8, 4096, 1024) fp32.
// cA[b,j,c] = (x[b,2j,c] + x[b,2j+1,c]) * k,  cD = (x_even - x_odd) * k
// d_out = [cA flat | cD flat].
//
// Measured history (kernel time):
//   NT/NT flags best (~60-72 us); cached paths 80+ us; stream count
//   (512 vs 2048 blocks) neutral; depth/hoisting neutral.
// This round: WRITE-BURST GROUPING. Previous versions interleaved
// cA/cD stores (streams 67 MB apart) -> every consecutive NT store flips
// DRAM context. Here: compute all 16 outputs into registers, then issue
// 8 consecutive ascending cA stores (32 KB) followed by 8 consecutive
// ascending cD stores (32 KB). Same traffic, same flags, 8x longer
// per-stream write bursts — the last mechanism separating this kernel
// from the 6.3-6.75 TB/s single-stream writers (copy/fill).

#define NPAIR (8 * 2048)        // total pair-rows
#define ROWS_PER_BLOCK 8
#define NPAIR_VEC (NPAIR * 256) // vec4 elements per output half

typedef float f4 __attribute__((ext_vector_type(4)));

__global__ __launch_bounds__(256) void dwt_haar_kernel(
    const f4* __restrict__ x,
    f4* __restrict__ cA,
    f4* __restrict__ cD)
{
    const float k = 0.7071067811865476f;
    const int t = threadIdx.x;                   // vec4 column 0..255
    const int r0 = blockIdx.x * ROWS_PER_BLOCK;  // first pair-row of block

    // Preload: 16 NT loads, ascending contiguous (64 KB per block).
    f4 a[ROWS_PER_BLOCK], b[ROWS_PER_BLOCK];
#pragma unroll
    for (int j = 0; j < ROWS_PER_BLOCK; ++j) {
        const int e = (r0 + j) * 512 + t;        // even input row, vec4 units
        a[j] = __builtin_nontemporal_load(&x[e]);
        b[j] = __builtin_nontemporal_load(&x[e + 256]);
    }

    // Compute everything into registers (reuse a/b as s/d to cap VGPRs).
#pragma unroll
    for (int j = 0; j < ROWS_PER_BLOCK; ++j) {
        const f4 s = (a[j] + b[j]) * k;
        const f4 d = (a[j] - b[j]) * k;
        a[j] = s;
        b[j] = d;
    }

    // Store grouped by stream: 8 ascending cA stores, then 8 ascending cD.
#pragma unroll
    for (int j = 0; j < ROWS_PER_BLOCK; ++j) {
        __builtin_nontemporal_store(a[j], &cA[(r0 + j) * 256 + t]);
    }
#pragma unroll
    for (int j = 0; j < ROWS_PER_BLOCK; ++j) {
        __builtin_nontemporal_store(b[j], &cD[(r0 + j) * 256 + t]);
    }
}

extern "C" void kernel_launch(void* const* d_in, const int* in_sizes, int n_in,
                              void* d_out, int out_size, void* d_ws, size_t ws_size,
                              hipStream_t stream)
{
    const f4* x = (const f4*)d_in[0];
    f4* cA = (f4*)d_out;
    f4* cD = cA + NPAIR_VEC;

    const int nblocks = NPAIR / ROWS_PER_BLOCK;  // 2048 = 8 blocks/CU
    dwt_haar_kernel<<<nblocks, 256, 0, stream>>>(x, cA, cD);
}